// Round 11
// baseline (4249.250 us; speedup 1.0000x reference)
//
#include <hip/hip_runtime.h>
#include <stdint.h>

#define EMBED  512
#define HIDDEN 512
#define VOCAB  32000
#define BATCH  64
#define NPIX   196
#define MAXLEN 32
#define NTILE  500      // 64-col fc tiles
#define NBLK   256
#define NGRP   16       // 16 groups x 16 blocks

typedef float f32x4 __attribute__((ext_vector_type(4)));
typedef short bf16x8 __attribute__((ext_vector_type(8)));
typedef unsigned short ushort_t;
typedef unsigned long long u64;

// ---------- helpers ----------
__device__ __forceinline__ u64 pack_key(float v, int idx) {
    unsigned u = __float_as_uint(v);
    u = (u & 0x80000000u) ? ~u : (u | 0x80000000u);   // monotone sortable map
    return ((u64)u << 32) | (unsigned)(~(unsigned)idx); // smaller idx wins ties
}
__device__ __forceinline__ ushort_t f2bf(float x) {           // round-to-nearest-even
    unsigned u = __float_as_uint(x);
    unsigned r = (u + 0x7fffu + ((u >> 16) & 1u)) >> 16;
    return (ushort_t)r;
}
__device__ __forceinline__ float bf2f(ushort_t h) {
    return __uint_as_float(((unsigned)h) << 16);
}
// fabric-coherent accessors (agent scope = coherence point; no fences needed)
__device__ __forceinline__ void cst32(unsigned* p, unsigned v) {
    __hip_atomic_store(p, v, __ATOMIC_RELAXED, __HIP_MEMORY_SCOPE_AGENT);
}
__device__ __forceinline__ unsigned cld32(const unsigned* p) {
    return __hip_atomic_load(p, __ATOMIC_RELAXED, __HIP_MEMORY_SCOPE_AGENT);
}
__device__ __forceinline__ u64 cld64(const u64* p) {
    return __hip_atomic_load(p, __ATOMIC_RELAXED, __HIP_MEMORY_SCOPE_AGENT);
}

// ---------- tree grid barrier: slot-per-instance, RMW polls (R10-proven) ----------
// Step barriers: NO threadfence. __syncthreads drains each wave's vmcnt, so all
// agent-scope stores are complete at the coherence point before arrival; readers
// use agent-scope loads that always read the coherence point.
__device__ __forceinline__ void grid_barrier(unsigned* barws, int k, bool fence) {
    __syncthreads();
    if (threadIdx.x == 0) {
        const int grp = blockIdx.x >> 4;
        const bool leader = (blockIdx.x & 15) == 0;
        unsigned* gc = barws + (k * NGRP + grp) * 16;
        unsigned* rc = barws + 16384 + k * 16;
        unsigned* gf = barws + 17408 + (k * NGRP + grp) * 16;
        if (fence) __threadfence();                       // one-time phase only
        else asm volatile("s_waitcnt vmcnt(0)" ::: "memory");
        if (!leader) {
            __hip_atomic_fetch_add(gc, 1u, __ATOMIC_RELAXED, __HIP_MEMORY_SCOPE_AGENT);
            while (__hip_atomic_fetch_add(gf, 0u, __ATOMIC_RELAXED, __HIP_MEMORY_SCOPE_AGENT) == 0u)
                __builtin_amdgcn_s_sleep(4);
        } else {
            while (__hip_atomic_fetch_add(gc, 0u, __ATOMIC_RELAXED, __HIP_MEMORY_SCOPE_AGENT) < 15u)
                __builtin_amdgcn_s_sleep(1);
            __hip_atomic_fetch_add(rc, 1u, __ATOMIC_RELAXED, __HIP_MEMORY_SCOPE_AGENT);
            while (__hip_atomic_fetch_add(rc, 0u, __ATOMIC_RELAXED, __HIP_MEMORY_SCOPE_AGENT) < (unsigned)NGRP)
                __builtin_amdgcn_s_sleep(1);
            __hip_atomic_fetch_add(gf, 1u, __ATOMIC_RELAXED, __HIP_MEMORY_SCOPE_AGENT);
        }
        asm volatile("" ::: "memory");
    }
    __syncthreads();
}

__global__ void ws_init(unsigned* barws, u64* kslab) {
    const int i = blockIdx.x * 256 + threadIdx.x;
    if (i < 33792) barws[i] = 0u;
    if (i < 31 * 1024) kslab[i] = 0ull;   // 31 steps x 64 rows x 16-u64 stride
}

// ---------- the whole decode, one persistent kernel ----------
__global__ __launch_bounds__(256) void decode_all(
    const float* __restrict__ enc,
    const int*   __restrict__ captions,
    const float* __restrict__ emb,
    const float* __restrict__ W_ih, const float* __restrict__ b_ih,
    const float* __restrict__ W_hh, const float* __restrict__ b_hh,
    const float* __restrict__ W_fc, const float* __restrict__ b_fc,
    const float* __restrict__ W_init_h, const float* __restrict__ b_init_h,
    const float* __restrict__ W_init_c, const float* __restrict__ b_init_c,
    float* __restrict__ out,
    unsigned* __restrict__ hf,      // [2][64][512] f32 bits (coherent)
    float* __restrict__ cbuf,       // block-local after fenced init
    unsigned* __restrict__ hpk,     // [64][512] {bf16 hi | bf16 lo<<16} (coherent)
    u64* __restrict__ kslab,        // [31][64][16] argmax keys (coherent, pre-zeroed)
    ushort_t* __restrict__ Whi, ushort_t* __restrict__ Wlo,
    unsigned* __restrict__ barws)
{
    // 33 KB LDS, phase-aliased: lstm h-chunk stage / fc split-K red + kred / init ssum
    __shared__ __align__(16) unsigned smem[8448];
    float* red  = (float*)smem;                 // [2][4096] fc pair-reduce
    u64*   kred = (u64*)(smem + 8192);          // [2][64] fc per-tile row max
    float* ssum = (float*)smem;                 // init summary

    const int blk = blockIdx.x, tid = threadIdx.x;
    const int lane = tid & 63, wid = tid >> 6;

    // ======== one-time: wsplit (all blocks, plain stores; fenced barrier 0) ========
    {
        const int nt4 = VOCAB * EMBED / 4;
        for (int i = blk * 256 + tid; i < nt4; i += NBLK * 256) {
            f32x4 w = ((const f32x4*)W_fc)[i];
            ushort_t hi[4], lo[4];
#pragma unroll
            for (int e = 0; e < 4; ++e) {
                hi[e] = f2bf(w[e]);
                lo[e] = f2bf(w[e] - bf2f(hi[e]));
            }
            *(uint64_t*)&Whi[i * 4] = *(const uint64_t*)hi;
            *(uint64_t*)&Wlo[i * 4] = *(const uint64_t*)lo;
        }
    }
    // ======== one-time: init (blocks 0..63) ========
    if (blk < BATCH) {
        const int b = blk;
        for (int k = tid; k < HIDDEN; k += 256) {
            float s = 0.f;
            const float* p = enc + (size_t)b * NPIX * HIDDEN + k;
            for (int px = 0; px < NPIX; ++px) s += p[(size_t)px * HIDDEN];
            ssum[k] = s * (1.0f / NPIX);
        }
        __syncthreads();
        for (int j = tid; j < HIDDEN; j += 256) {
            const f32x4* wh = (const f32x4*)(W_init_h + (size_t)j * HIDDEN);
            const f32x4* wc = (const f32x4*)(W_init_c + (size_t)j * HIDDEN);
            float ah = 0.f, ac = 0.f;
            for (int k4 = 0; k4 < HIDDEN / 4; ++k4) {
                f32x4 s4 = *(const f32x4*)&ssum[k4 * 4];
                f32x4 a = wh[k4], cc = wc[k4];
                ah += s4[0]*a[0] + s4[1]*a[1] + s4[2]*a[2] + s4[3]*a[3];
                ac += s4[0]*cc[0] + s4[1]*cc[1] + s4[2]*cc[2] + s4[3]*cc[3];
            }
            hf[b * HIDDEN + j] = __float_as_uint(ah + b_init_h[j]);   // slab 0, plain (fenced)
            cbuf[b * HIDDEN + j] = ac + b_init_c[j];
        }
        f32x4* o4 = (f32x4*)(out + (size_t)b * MAXLEN * VOCAB);
        f32x4 z = {0.f, 0.f, 0.f, 0.f};
        for (int i = tid; i < VOCAB / 4; i += 256) __builtin_nontemporal_store(z, &o4[i]);
    }
    grid_barrier(barws, 0, true);

    // ======== 31 decode steps ========
    for (int t = 0; t < MAXLEN - 1; ++t) {
        const unsigned* hfin = hf + (t & 1) * 32768;
        unsigned*       hfout = hf + ((t + 1) & 1) * 32768;

        // ---------- LSTM phase (all 256 blocks; units u0 = blk*2, u0+1) ----------
        {
            const int u0 = blk * 2;
            const int b = tid >> 2, q = tid & 3;

            int tok;
            if (t == 0) tok = captions[b * MAXLEN];
            else {
                u64 km = cld64(kslab + (size_t)(t - 1) * 1024 + b * 16);
                tok = (int)(~(unsigned)(km & 0xffffffffull));
            }

            const f32x4* x4 = (const f32x4*)(emb + (size_t)tok * EMBED);
            const int j_0 = q * HIDDEN + u0;
            const f32x4* wiA = (const f32x4*)(W_ih + (size_t)j_0 * EMBED);
            const f32x4* wiB = wiA + EMBED / 4;
            const f32x4* whA = (const f32x4*)(W_hh + (size_t)j_0 * HIDDEN);
            const f32x4* whB = whA + HIDDEN / 4;

            float a0 = 0.f, a1 = 0.f;
            for (int c = 0; c < 4; ++c) {               // 128-unit h chunks via LDS
#pragma unroll
                for (int i = 0; i < 32; ++i) {
                    const int idx = tid + i * 256;      // 0..8191
                    const int row = idx >> 7, col = idx & 127;
                    smem[idx] = cld32(hfin + row * HIDDEN + c * 128 + col);
                }
                __syncthreads();
                const float* hs = (const float*)smem + b * 128;
#pragma unroll 4
                for (int k4 = 0; k4 < 32; ++k4) {
                    const int kg = c * 32 + k4;
                    f32x4 xv = x4[kg];
                    f32x4 hv = *(const f32x4*)&hs[k4 * 4];
                    f32x4 wA = wiA[kg], wB = wiB[kg], vA = whA[kg], vB = whB[kg];
                    a0 += xv[0]*wA[0] + xv[1]*wA[1] + xv[2]*wA[2] + xv[3]*wA[3]
                        + hv[0]*vA[0] + hv[1]*vA[1] + hv[2]*vA[2] + hv[3]*vA[3];
                    a1 += xv[0]*wB[0] + xv[1]*wB[1] + xv[2]*wB[2] + xv[3]*wB[3]
                        + hv[0]*vB[0] + hv[1]*vB[1] + hv[2]*vB[2] + hv[3]*vB[3];
                }
                __syncthreads();
            }
            a0 += b_ih[j_0] + b_hh[j_0];
            a1 += b_ih[j_0 + 1] + b_hh[j_0 + 1];

            const int base = lane & ~3;
#pragma unroll
            for (int uu = 0; uu < 2; ++uu) {
                float g  = (uu == 0) ? a0 : a1;
                float gi = __shfl(g, base + 0, 64);
                float gfv = __shfl(g, base + 1, 64);
                float gg = __shfl(g, base + 2, 64);
                float go = __shfl(g, base + 3, 64);
                if (q == uu) {
                    const int u = u0 + uu;
                    float i_ = 1.f / (1.f + expf(-gi));
                    float f_ = 1.f / (1.f + expf(-gfv));
                    float o_ = 1.f / (1.f + expf(-go));
                    float g_ = tanhf(gg);
                    float cv = cbuf[b * HIDDEN + u];
                    float c2 = f_ * cv + i_ * g_;
                    float h2 = o_ * tanhf(c2);
                    cbuf[b * HIDDEN + u] = c2;
                    ushort_t hh = f2bf(h2);
                    ushort_t hl = f2bf(h2 - bf2f(hh));
                    cst32(hfout + b * HIDDEN + u, __float_as_uint(h2));
                    cst32(hpk + b * HIDDEN + u, (unsigned)hh | ((unsigned)hl << 16));
                }
            }
        }
        grid_barrier(barws, 1 + 2 * t, false);

        // ---------- FC phase (blocks 0..249; 2 tiles/block, split-K x2) ----------
        if (blk < NTILE / 2) {
            const int tileSel = wid >> 1, khalf = wid & 1;
            const int tileIdx = blk * 2 + tileSel;
            const int n0 = tileIdx * 64;
            const int r16 = lane & 15, g = lane >> 4;

            f32x4 acc[4][4];
#pragma unroll
            for (int i = 0; i < 4; ++i)
#pragma unroll
                for (int j = 0; j < 4; ++j) acc[i][j] = (f32x4){0.f, 0.f, 0.f, 0.f};

            const u64* hpk64 = (const u64*)hpk;
            const ushort_t* hb = Whi + (size_t)(n0 + r16) * EMBED + g * 8;
            const ushort_t* lb = Wlo + (size_t)(n0 + r16) * EMBED + g * 8;

            union FR { bf16x8 v; unsigned w[4]; };

            const int kb0 = khalf * 8;
            for (int kb = kb0; kb < kb0 + 8; ++kb) {
                const int ko = kb * 32;
                bf16x8 Ah[4], Al[4], Bh[4], Bl[4];
#pragma unroll
                for (int mt = 0; mt < 4; ++mt) {
                    const u64* hp = hpk64 + (size_t)(mt * 16 + r16) * 256 + kb * 16 + g * 4;
                    FR fh, fl;
#pragma unroll
                    for (int j = 0; j < 4; ++j) {
                        u64 L = cld64(hp + j);
                        unsigned d0 = (unsigned)L, d1 = (unsigned)(L >> 32);
                        fh.w[j] = (d0 & 0xFFFFu) | (d1 << 16);
                        fl.w[j] = (d0 >> 16) | (d1 & 0xFFFF0000u);
                    }
                    Ah[mt] = fh.v; Al[mt] = fl.v;
                }
#pragma unroll
                for (int nt = 0; nt < 4; ++nt) {
                    Bh[nt] = *(const bf16x8*)(hb + (size_t)nt * 16 * EMBED + ko);
                    Bl[nt] = *(const bf16x8*)(lb + (size_t)nt * 16 * EMBED + ko);
                }
#pragma unroll
                for (int mt = 0; mt < 4; ++mt)
#pragma unroll
                    for (int nt = 0; nt < 4; ++nt) {
                        acc[mt][nt] = __builtin_amdgcn_mfma_f32_16x16x32_bf16(Al[mt], Bh[nt], acc[mt][nt], 0, 0, 0);
                        acc[mt][nt] = __builtin_amdgcn_mfma_f32_16x16x32_bf16(Ah[mt], Bl[nt], acc[mt][nt], 0, 0, 0);
                        acc[mt][nt] = __builtin_amdgcn_mfma_f32_16x16x32_bf16(Ah[mt], Bh[nt], acc[mt][nt], 0, 0, 0);
                    }
            }

            if (khalf) {
#pragma unroll
                for (int mt = 0; mt < 4; ++mt)
#pragma unroll
                    for (int nt = 0; nt < 4; ++nt)
#pragma unroll
                        for (int reg = 0; reg < 4; ++reg)
                            red[tileSel * 4096 + ((mt * 4 + nt) * 4 + reg) * 64 + lane] = acc[mt][nt][reg];
            }
            __syncthreads();
            if (!khalf) {
#pragma unroll
                for (int mt = 0; mt < 4; ++mt)
#pragma unroll
                    for (int nt = 0; nt < 4; ++nt)
#pragma unroll
                        for (int reg = 0; reg < 4; ++reg)
                            acc[mt][nt][reg] += red[tileSel * 4096 + ((mt * 4 + nt) * 4 + reg) * 64 + lane];

                float bias[4];
#pragma unroll
                for (int nt = 0; nt < 4; ++nt) bias[nt] = b_fc[n0 + nt * 16 + r16];

#pragma unroll
                for (int mt = 0; mt < 4; ++mt)
#pragma unroll
                    for (int reg = 0; reg < 4; ++reg) {
                        const int row = mt * 16 + g * 4 + reg;
                        float* op = &out[(size_t)row * (MAXLEN * VOCAB) + (size_t)(t + 1) * VOCAB];
                        u64 km = 0ull;
#pragma unroll
                        for (int nt = 0; nt < 4; ++nt) {
                            const int col = n0 + nt * 16 + r16;
                            float v = acc[mt][nt][reg] + bias[nt];
                            __builtin_nontemporal_store(v, op + col);
                            u64 kk = pack_key(v, col);
                            km = kk > km ? kk : km;
                        }
#pragma unroll
                        for (int msk = 8; msk >= 1; msk >>= 1) {
                            u64 o = __shfl_xor(km, msk, 64);
                            km = km > o ? km : o;
                        }
                        if (r16 == 0) kred[tileSel * 64 + row] = km;   // LDS, per tile
                    }
            }
            __syncthreads();
            if (wid == 0) {   // merge 2 tiles, one padded-line atomicMax per row
                const int row = lane;
                u64 k0 = kred[row], k1 = kred[64 + row];
                u64 km = k0 > k1 ? k0 : k1;
                __hip_atomic_fetch_max(kslab + (size_t)t * 1024 + row * 16, km,
                                       __ATOMIC_RELAXED, __HIP_MEMORY_SCOPE_AGENT);
            }
        }
        grid_barrier(barws, 2 + 2 * t, false);
    }
}

extern "C" void kernel_launch(void* const* d_in, const int* in_sizes, int n_in,
                              void* d_out, int out_size, void* d_ws, size_t ws_size,
                              hipStream_t stream) {
    const float* enc       = (const float*)d_in[0];
    const int*   captions  = (const int*)  d_in[1];
    const float* emb       = (const float*)d_in[2];
    const float* W_ih      = (const float*)d_in[3];
    const float* b_ih      = (const float*)d_in[4];
    const float* W_hh      = (const float*)d_in[5];
    const float* b_hh      = (const float*)d_in[6];
    const float* W_fc      = (const float*)d_in[7];
    const float* b_fc      = (const float*)d_in[8];
    const float* W_init_h  = (const float*)d_in[9];
    const float* b_init_h  = (const float*)d_in[10];
    const float* W_init_c  = (const float*)d_in[11];
    const float* b_init_c  = (const float*)d_in[12];
    float* out = (float*)d_out;

    char* wsb = (char*)d_ws;
    unsigned* hf   = (unsigned*)(wsb + 0);        // 2 x 131072B
    float*    cbuf = (float*)(wsb + 262144);      // 131072B
    unsigned* hpk  = (unsigned*)(wsb + 393216);   // 131072B -> ends 524288
    u64*      kslab= (u64*)(wsb + 524288);        // 253952B -> ends 778240
    unsigned* barws= (unsigned*)(wsb + 786432);   // 135168B -> ends 921600
    ushort_t* Whi  = (ushort_t*)(wsb + 1048576);  // 32768000B -> ends 33816576
    ushort_t* Wlo  = (ushort_t*)(wsb + 33816576); // 32768000B -> ends 66584576

    ws_init<<<132, 256, 0, stream>>>(barws, kslab);
    decode_all<<<NBLK, 256, 0, stream>>>(
        enc, captions, emb, W_ih, b_ih, W_hh, b_hh, W_fc, b_fc,
        W_init_h, b_init_h, W_init_c, b_init_c,
        out, hf, cbuf, hpk, kslab, Whi, Wlo, barws);
}

// Round 12
// 3049.925 us; speedup vs baseline: 1.3932x; 1.3932x over previous
//
#include <hip/hip_runtime.h>
#include <stdint.h>

#define EMBED  512
#define HIDDEN 512
#define VOCAB  32000
#define BATCH  64
#define NPIX   196
#define MAXLEN 32
#define NBLK   256
#define NTHR   512
#define NGRP   16       // 16 groups x 16 blocks (barrier tree)

typedef float f32x4 __attribute__((ext_vector_type(4)));
typedef short bf16x8 __attribute__((ext_vector_type(8)));
typedef unsigned short ushort_t;
typedef unsigned long long u64;

// ---------- helpers ----------
__device__ __forceinline__ u64 pack_key(float v, int idx) {
    unsigned u = __float_as_uint(v);
    u = (u & 0x80000000u) ? ~u : (u | 0x80000000u);   // monotone sortable map
    return ((u64)u << 32) | (unsigned)(~(unsigned)idx); // smaller idx wins ties
}
__device__ __forceinline__ ushort_t f2bf(float x) {           // round-to-nearest-even
    unsigned u = __float_as_uint(x);
    unsigned r = (u + 0x7fffu + ((u >> 16) & 1u)) >> 16;
    return (ushort_t)r;
}
__device__ __forceinline__ float bf2f(ushort_t h) {
    return __uint_as_float(((unsigned)h) << 16);
}
__device__ __forceinline__ void cst32(unsigned* p, unsigned v) {
    __hip_atomic_store(p, v, __ATOMIC_RELAXED, __HIP_MEMORY_SCOPE_AGENT);
}
__device__ __forceinline__ unsigned cld32(const unsigned* p) {
    return __hip_atomic_load(p, __ATOMIC_RELAXED, __HIP_MEMORY_SCOPE_AGENT);
}
__device__ __forceinline__ u64 cld64(const u64* p) {
    return __hip_atomic_load(p, __ATOMIC_RELAXED, __HIP_MEMORY_SCOPE_AGENT);
}

// ---------- tree grid barrier (R10/R11-proven): slot-per-instance, RMW polls ----------
__device__ __forceinline__ void grid_barrier(unsigned* barws, int k, bool fence) {
    __syncthreads();
    if (threadIdx.x == 0) {
        const int grp = blockIdx.x >> 4;
        const bool leader = (blockIdx.x & 15) == 0;
        unsigned* gc = barws + (k * NGRP + grp) * 16;
        unsigned* rc = barws + 16384 + k * 16;
        unsigned* gf = barws + 17408 + (k * NGRP + grp) * 16;
        if (fence) __threadfence();
        else asm volatile("s_waitcnt vmcnt(0)" ::: "memory");
        if (!leader) {
            __hip_atomic_fetch_add(gc, 1u, __ATOMIC_RELAXED, __HIP_MEMORY_SCOPE_AGENT);
            while (__hip_atomic_fetch_add(gf, 0u, __ATOMIC_RELAXED, __HIP_MEMORY_SCOPE_AGENT) == 0u)
                __builtin_amdgcn_s_sleep(4);
        } else {
            while (__hip_atomic_fetch_add(gc, 0u, __ATOMIC_RELAXED, __HIP_MEMORY_SCOPE_AGENT) < 15u)
                __builtin_amdgcn_s_sleep(1);
            __hip_atomic_fetch_add(rc, 1u, __ATOMIC_RELAXED, __HIP_MEMORY_SCOPE_AGENT);
            while (__hip_atomic_fetch_add(rc, 0u, __ATOMIC_RELAXED, __HIP_MEMORY_SCOPE_AGENT) < (unsigned)NGRP)
                __builtin_amdgcn_s_sleep(1);
            __hip_atomic_fetch_add(gf, 1u, __ATOMIC_RELAXED, __HIP_MEMORY_SCOPE_AGENT);
        }
        asm volatile("" ::: "memory");
    }
    __syncthreads();
}

__global__ void ws_init(unsigned* barws, u64* kslab) {
    const int i = blockIdx.x * 256 + threadIdx.x;
    if (i < 33792) barws[i] = 0u;
    if (i < 31 * 1024) kslab[i] = 0ull;      // 31 steps x 64 rows x 16-u64 stride
}

// ---------- the whole decode, one persistent kernel ----------
// 256 blocks x 512 threads, 1 block/CU (2 waves/SIMD).
// fc W lives in REGISTERS (128 VGPR/lane, split from fp32 once).
// lstm W rows live in LDS (32 KB/block, loaded once).
__global__ __launch_bounds__(512, 2) void decode_all(
    const float* __restrict__ enc,
    const int*   __restrict__ captions,
    const float* __restrict__ emb,
    const float* __restrict__ W_ih, const float* __restrict__ b_ih,
    const float* __restrict__ W_hh, const float* __restrict__ b_hh,
    const float* __restrict__ W_fc, const float* __restrict__ b_fc,
    const float* __restrict__ W_init_h, const float* __restrict__ b_init_h,
    const float* __restrict__ W_init_c, const float* __restrict__ b_init_c,
    float* __restrict__ out,
    unsigned* __restrict__ hf,      // [2][64][512] f32 bits (coherent)
    float* __restrict__ cbuf,       // block-owned units after fenced init
    unsigned* __restrict__ hhi32,   // [64][256] 2xbf16 packed (coherent)
    unsigned* __restrict__ hlo32,
    u64* __restrict__ kslab,        // [31][64][16] argmax keys (pre-zeroed)
    unsigned* __restrict__ barws)
{
    __shared__ float wlds[8192];                      // 32 KB persistent lstm W
    __shared__ __align__(16) float smem[24576];       // 96 KB transient
    __shared__ u64 kredl[128];                        // 1 KB fc key merge

    const int blk = blockIdx.x, tid = threadIdx.x;
    const int lane = tid & 63, w = tid >> 6;
    const int u0 = blk * 2;

    // ---- one-time: lstm W rows -> LDS ----
    for (int i = tid; i < 8192; i += NTHR) {
        const int rowp = i >> 10, off = i & 1023;     // rowp = uu*4+q
        const int uu = rowp >> 2, q = rowp & 3;
        const int j = q * HIDDEN + u0 + uu;
        wlds[i] = (off < 512) ? W_ih[(size_t)j * 512 + off]
                              : W_hh[(size_t)j * 512 + off - 512];
    }

    // ---- one-time: fc W -> registers (blocks < 250) ----
    const int r16 = lane & 15, g = lane >> 4;
    const int tsel = w >> 2, ks = w & 3;
    const int tileIdx = blk * 2 + tsel;
    const int n0 = tileIdx * 64;
    bf16x8 WH[4][4], WL[4][4];
    if (blk < 250) {
#pragma unroll
        for (int kb = 0; kb < 4; ++kb)
#pragma unroll
            for (int nt = 0; nt < 4; ++nt) {
                const float* src = W_fc + (size_t)(n0 + nt * 16 + r16) * 512
                                 + ks * 128 + kb * 32 + g * 8;
                f32x4 w0 = *(const f32x4*)src;
                f32x4 w1 = *(const f32x4*)(src + 4);
                union { ushort_t s[8]; bf16x8 v; } uh, ul;
#pragma unroll
                for (int e = 0; e < 4; ++e) {
                    uh.s[e]     = f2bf(w0[e]); ul.s[e]     = f2bf(w0[e] - bf2f(uh.s[e]));
                    uh.s[4 + e] = f2bf(w1[e]); ul.s[4 + e] = f2bf(w1[e] - bf2f(uh.s[4 + e]));
                }
                WH[kb][nt] = uh.v; WL[kb][nt] = ul.v;
            }
    }

    // ---- one-time: init (blocks 0..63): summary, h0, c0, zero out[:,0,:] ----
    if (blk < BATCH) {
        const int b = blk;
        if (tid < HIDDEN) {
            float s = 0.f;
            const float* p = enc + (size_t)b * NPIX * HIDDEN + tid;
            for (int px = 0; px < NPIX; ++px) s += p[(size_t)px * HIDDEN];
            smem[tid] = s * (1.0f / NPIX);
        }
        __syncthreads();
        if (tid < HIDDEN) {
            const int j = tid;
            const f32x4* wh = (const f32x4*)(W_init_h + (size_t)j * HIDDEN);
            const f32x4* wc = (const f32x4*)(W_init_c + (size_t)j * HIDDEN);
            float ah = 0.f, ac = 0.f;
            for (int k4 = 0; k4 < HIDDEN / 4; ++k4) {
                f32x4 s4 = *(const f32x4*)&smem[k4 * 4];
                f32x4 a = wh[k4], cc = wc[k4];
                ah += s4[0]*a[0] + s4[1]*a[1] + s4[2]*a[2] + s4[3]*a[3];
                ac += s4[0]*cc[0] + s4[1]*cc[1] + s4[2]*cc[2] + s4[3]*cc[3];
            }
            hf[b * HIDDEN + j] = __float_as_uint(ah + b_init_h[j]);   // plain (fenced bar)
            cbuf[b * HIDDEN + j] = ac + b_init_c[j];
        }
        f32x4* o4 = (f32x4*)(out + (size_t)b * MAXLEN * VOCAB);
        f32x4 z = {0.f, 0.f, 0.f, 0.f};
        for (int i = tid; i < VOCAB / 4; i += NTHR) __builtin_nontemporal_store(z, &o4[i]);
    }
    grid_barrier(barws, 0, true);

    // ======== 31 decode steps ========
    for (int t = 0; t < MAXLEN - 1; ++t) {
        const unsigned* hfin  = hf + (t & 1) * 32768;
        unsigned*       hfout = hf + ((t + 1) & 1) * 32768;

        // ---------- LSTM phase (all blocks; units u0, u0+1) ----------
        {
            const int b = tid >> 3, r = tid & 7, uu = r >> 2, q = r & 3;
            const int rowp = uu * 4 + q;
            const int j = q * HIDDEN + u0 + uu;

            int tok;
            if (t == 0) tok = captions[b * MAXLEN];
            else {
                u64 km = cld64(kslab + (size_t)(t - 1) * 1024 + b * 16);
                tok = (int)(~(unsigned)(km & 0xffffffffull));
            }

            const f32x4* x4 = (const f32x4*)(emb + (size_t)tok * EMBED);
            const f32x4* wih4 = (const f32x4*)(wlds + rowp * 1024);
            const f32x4* whh4 = wih4 + 128;

            float a = 0.f;
            for (int c = 0; c < 4; ++c) {
                __syncthreads();
                for (int i = tid; i < 8192; i += NTHR) {
                    const int rr = i >> 7, cc = i & 127;
                    ((unsigned*)smem)[i] = cld32(hfin + rr * HIDDEN + c * 128 + cc);
                }
                __syncthreads();
                const float* hs = smem + b * 128;
#pragma unroll 4
                for (int k4 = 0; k4 < 32; ++k4) {
                    const int kg = c * 32 + k4;
                    f32x4 xv = x4[kg];
                    f32x4 hv = *(const f32x4*)&hs[k4 * 4];
                    f32x4 wA = wih4[kg], vA = whh4[kg];
                    a += xv[0]*wA[0] + xv[1]*wA[1] + xv[2]*wA[2] + xv[3]*wA[3]
                       + hv[0]*vA[0] + hv[1]*vA[1] + hv[2]*vA[2] + hv[3]*vA[3];
                }
            }
            a += b_ih[j] + b_hh[j];

            const int base = (lane & ~7) + uu * 4;
            float gi  = __shfl(a, base + 0, 64);
            float gfv = __shfl(a, base + 1, 64);
            float gg  = __shfl(a, base + 2, 64);
            float go  = __shfl(a, base + 3, 64);
            float i_ = 1.f / (1.f + expf(-gi));
            float f_ = 1.f / (1.f + expf(-gfv));
            float o_ = 1.f / (1.f + expf(-go));
            float g_ = tanhf(gg);
            float cv = cbuf[b * HIDDEN + u0 + uu];
            float c2 = f_ * cv + i_ * g_;
            float h2 = o_ * tanhf(c2);
            if (q == 0) cbuf[b * HIDDEN + u0 + uu] = c2;
            float h2o = __shfl(h2, (lane & ~7) + 4, 64);   // uu=1 value
            if (r == 0) {
                ushort_t h0h = f2bf(h2),             h1h = f2bf(h2o);
                ushort_t h0l = f2bf(h2 - bf2f(h0h)), h1l = f2bf(h2o - bf2f(h1h));
                cst32(hhi32 + ((b * HIDDEN + u0) >> 1), (unsigned)h0h | ((unsigned)h1h << 16));
                cst32(hlo32 + ((b * HIDDEN + u0) >> 1), (unsigned)h0l | ((unsigned)h1l << 16));
                cst32(hfout + b * HIDDEN + u0,     __float_as_uint(h2));
                cst32(hfout + b * HIDDEN + u0 + 1, __float_as_uint(h2o));
            }
        }
        grid_barrier(barws, 1 + 2 * t, false);

        // ---------- FC phase (blocks 0..249; 2 tiles, 4-wave split-K each) ----------
        if (blk < 250) {
            f32x4 acc[4][4];
#pragma unroll
            for (int i = 0; i < 4; ++i)
#pragma unroll
                for (int jj = 0; jj < 4; ++jj) acc[i][jj] = (f32x4){0.f, 0.f, 0.f, 0.f};

            const u64* hhi64 = (const u64*)hhi32;
            const u64* hlo64 = (const u64*)hlo32;

#pragma unroll
            for (int kb = 0; kb < 4; ++kb) {
                const int khere = ks * 128 + kb * 32 + g * 8;
                bf16x8 Ah[4], Al[4];
#pragma unroll
                for (int mt = 0; mt < 4; ++mt) {
                    const size_t bidx = ((size_t)(mt * 16 + r16) * 512 + khere) >> 2;
                    union { u64 d[2]; bf16x8 v; } fh, fl;
                    fh.d[0] = cld64(hhi64 + bidx); fh.d[1] = cld64(hhi64 + bidx + 1);
                    fl.d[0] = cld64(hlo64 + bidx); fl.d[1] = cld64(hlo64 + bidx + 1);
                    Ah[mt] = fh.v; Al[mt] = fl.v;
                }
#pragma unroll
                for (int mt = 0; mt < 4; ++mt)
#pragma unroll
                    for (int nt = 0; nt < 4; ++nt) {
                        acc[mt][nt] = __builtin_amdgcn_mfma_f32_16x16x32_bf16(Al[mt], WH[kb][nt], acc[mt][nt], 0, 0, 0);
                        acc[mt][nt] = __builtin_amdgcn_mfma_f32_16x16x32_bf16(Ah[mt], WL[kb][nt], acc[mt][nt], 0, 0, 0);
                        acc[mt][nt] = __builtin_amdgcn_mfma_f32_16x16x32_bf16(Ah[mt], WH[kb][nt], acc[mt][nt], 0, 0, 0);
                    }
            }

            // split-K reduce: waves ks=1..3 dump; wave ks=0 sums + epilogue
            if (ks != 0) {
                float* slab = smem + tsel * 12288 + (ks - 1) * 4096;
#pragma unroll
                for (int mt = 0; mt < 4; ++mt)
#pragma unroll
                    for (int nt = 0; nt < 4; ++nt)
#pragma unroll
                        for (int reg = 0; reg < 4; ++reg)
                            slab[((mt * 4 + nt) * 4 + reg) * 64 + lane] = acc[mt][nt][reg];
            }
            __syncthreads();
            if (ks == 0) {
                const float* slabs = smem + tsel * 12288;
#pragma unroll
                for (int mt = 0; mt < 4; ++mt)
#pragma unroll
                    for (int nt = 0; nt < 4; ++nt)
#pragma unroll
                        for (int reg = 0; reg < 4; ++reg) {
                            const int idx = ((mt * 4 + nt) * 4 + reg) * 64 + lane;
                            acc[mt][nt][reg] += slabs[idx] + slabs[4096 + idx] + slabs[8192 + idx];
                        }

                float bias[4];
#pragma unroll
                for (int nt = 0; nt < 4; ++nt) bias[nt] = b_fc[n0 + nt * 16 + r16];

#pragma unroll
                for (int mt = 0; mt < 4; ++mt)
#pragma unroll
                    for (int reg = 0; reg < 4; ++reg) {
                        const int row = mt * 16 + g * 4 + reg;
                        float* op = &out[(size_t)row * (MAXLEN * VOCAB) + (size_t)(t + 1) * VOCAB];
                        u64 km = 0ull;
#pragma unroll
                        for (int nt = 0; nt < 4; ++nt) {
                            const int col = n0 + nt * 16 + r16;
                            float v = acc[mt][nt][reg] + bias[nt];
                            __builtin_nontemporal_store(v, op + col);
                            u64 kk = pack_key(v, col);
                            km = kk > km ? kk : km;
                        }
#pragma unroll
                        for (int msk = 8; msk >= 1; msk >>= 1) {
                            u64 o = __shfl_xor(km, msk, 64);
                            km = km > o ? km : o;
                        }
                        if (r16 == 0) kredl[tsel * 64 + row] = km;
                    }
            }
            __syncthreads();
            if (w == 0) {   // merge 2 tiles, fire-and-forget fetch_max per row line
                const int row = lane;
                u64 k0 = kredl[row], k1 = kredl[64 + row];
                u64 km = k0 > k1 ? k0 : k1;
                __hip_atomic_fetch_max(kslab + (size_t)t * 1024 + row * 16, km,
                                       __ATOMIC_RELAXED, __HIP_MEMORY_SCOPE_AGENT);
            }
        }
        grid_barrier(barws, 2 + 2 * t, false);
    }
}

extern "C" void kernel_launch(void* const* d_in, const int* in_sizes, int n_in,
                              void* d_out, int out_size, void* d_ws, size_t ws_size,
                              hipStream_t stream) {
    const float* enc       = (const float*)d_in[0];
    const int*   captions  = (const int*)  d_in[1];
    const float* emb       = (const float*)d_in[2];
    const float* W_ih      = (const float*)d_in[3];
    const float* b_ih      = (const float*)d_in[4];
    const float* W_hh      = (const float*)d_in[5];
    const float* b_hh      = (const float*)d_in[6];
    const float* W_fc      = (const float*)d_in[7];
    const float* b_fc      = (const float*)d_in[8];
    const float* W_init_h  = (const float*)d_in[9];
    const float* b_init_h  = (const float*)d_in[10];
    const float* W_init_c  = (const float*)d_in[11];
    const float* b_init_c  = (const float*)d_in[12];
    float* out = (float*)d_out;

    char* wsb = (char*)d_ws;
    unsigned* hf    = (unsigned*)(wsb + 0);        // 262144B
    float*    cbuf  = (float*)(wsb + 262144);      // 131072B
    unsigned* hhi32 = (unsigned*)(wsb + 393216);   // 65536B
    unsigned* hlo32 = (unsigned*)(wsb + 458752);   // 65536B
    u64*      kslab = (u64*)(wsb + 524288);        // 253952B -> ends 778240
    unsigned* barws = (unsigned*)(wsb + 786432);   // 135168B -> ends 921600

    ws_init<<<132, 256, 0, stream>>>(barws, kslab);
    decode_all<<<NBLK, NTHR, 0, stream>>>(
        enc, captions, emb, W_ih, b_ih, W_hh, b_hh, W_fc, b_fc,
        W_init_h, b_init_h, W_init_c, b_init_c,
        out, hf, cbuf, hhi32, hlo32, kslab, barws);
}

// Round 13
// 2547.718 us; speedup vs baseline: 1.6679x; 1.1971x over previous
//
#include <hip/hip_runtime.h>
#include <stdint.h>

#define EMBED  512
#define HIDDEN 512
#define VOCAB  32000
#define BATCH  64
#define NPIX   196
#define MAXLEN 32
#define NBLK   256
#define NTHR   512
#define NGRP   16       // 16 groups x 16 blocks (barrier tree)

typedef float f32x4 __attribute__((ext_vector_type(4)));
typedef short bf16x8 __attribute__((ext_vector_type(8)));
typedef unsigned short ushort_t;
typedef unsigned long long u64;

// ---------- helpers ----------
__device__ __forceinline__ u64 pack_key(float v, int idx) {
    unsigned u = __float_as_uint(v);
    u = (u & 0x80000000u) ? ~u : (u | 0x80000000u);   // monotone sortable map
    return ((u64)u << 32) | (unsigned)(~(unsigned)idx); // smaller idx wins ties
}
__device__ __forceinline__ ushort_t f2bf(float x) {           // round-to-nearest-even
    unsigned u = __float_as_uint(x);
    unsigned r = (u + 0x7fffu + ((u >> 16) & 1u)) >> 16;
    return (ushort_t)r;
}
__device__ __forceinline__ float bf2f(ushort_t h) {
    return __uint_as_float(((unsigned)h) << 16);
}
__device__ __forceinline__ void cst32(unsigned* p, unsigned v) {
    __hip_atomic_store(p, v, __ATOMIC_RELAXED, __HIP_MEMORY_SCOPE_AGENT);
}
__device__ __forceinline__ unsigned cld32(const unsigned* p) {
    return __hip_atomic_load(p, __ATOMIC_RELAXED, __HIP_MEMORY_SCOPE_AGENT);
}
__device__ __forceinline__ u64 cld64(const u64* p) {
    return __hip_atomic_load(p, __ATOMIC_RELAXED, __HIP_MEMORY_SCOPE_AGENT);
}

// ---------- tree grid barrier (R10/R11-proven): slot-per-instance, RMW polls ----------
__device__ __forceinline__ void grid_barrier(unsigned* barws, int k, bool fence) {
    __syncthreads();
    if (threadIdx.x == 0) {
        const int grp = blockIdx.x >> 4;
        const bool leader = (blockIdx.x & 15) == 0;
        unsigned* gc = barws + (k * NGRP + grp) * 16;
        unsigned* rc = barws + 16384 + k * 16;
        unsigned* gf = barws + 17408 + (k * NGRP + grp) * 16;
        if (fence) __threadfence();
        else asm volatile("s_waitcnt vmcnt(0)" ::: "memory");
        if (!leader) {
            __hip_atomic_fetch_add(gc, 1u, __ATOMIC_RELAXED, __HIP_MEMORY_SCOPE_AGENT);
            while (__hip_atomic_fetch_add(gf, 0u, __ATOMIC_RELAXED, __HIP_MEMORY_SCOPE_AGENT) == 0u)
                __builtin_amdgcn_s_sleep(4);
        } else {
            while (__hip_atomic_fetch_add(gc, 0u, __ATOMIC_RELAXED, __HIP_MEMORY_SCOPE_AGENT) < 15u)
                __builtin_amdgcn_s_sleep(1);
            __hip_atomic_fetch_add(rc, 1u, __ATOMIC_RELAXED, __HIP_MEMORY_SCOPE_AGENT);
            while (__hip_atomic_fetch_add(rc, 0u, __ATOMIC_RELAXED, __HIP_MEMORY_SCOPE_AGENT) < (unsigned)NGRP)
                __builtin_amdgcn_s_sleep(1);
            __hip_atomic_fetch_add(gf, 1u, __ATOMIC_RELAXED, __HIP_MEMORY_SCOPE_AGENT);
        }
        asm volatile("" ::: "memory");
    }
    __syncthreads();
}

__global__ void ws_init(unsigned* barws, u64* kslab) {
    const int i = blockIdx.x * 256 + threadIdx.x;
    if (i < 33792) barws[i] = 0u;
    if (i < 31 * 1024) kslab[i] = 0ull;      // 31 steps x 64 rows x 16-u64 stride
}

// ---------- the whole decode, one persistent kernel ----------
// 256 blocks x 512 threads, 1 block/CU (2 waves/SIMD).
// lstm W in LDS (padded rows, 2-way max bank aliasing); fc W pre-split bf16 in ws.
__global__ __launch_bounds__(512, 2) void decode_all(
    const float* __restrict__ enc,
    const int*   __restrict__ captions,
    const float* __restrict__ emb,
    const float* __restrict__ W_ih, const float* __restrict__ b_ih,
    const float* __restrict__ W_hh, const float* __restrict__ b_hh,
    const float* __restrict__ W_fc, const float* __restrict__ b_fc,
    const float* __restrict__ W_init_h, const float* __restrict__ b_init_h,
    const float* __restrict__ W_init_c, const float* __restrict__ b_init_c,
    float* __restrict__ out,
    unsigned* __restrict__ hf,      // [2][64][512] f32 bits (coherent)
    float* __restrict__ cbuf,       // block-owned units after fenced init
    unsigned* __restrict__ hhi32,   // [64][256] 2xbf16 packed (coherent)
    unsigned* __restrict__ hlo32,
    u64* __restrict__ kslab,        // [31][64][16] argmax keys (pre-zeroed)
    ushort_t* __restrict__ Whi, ushort_t* __restrict__ Wlo,
    unsigned* __restrict__ barws)
{
    __shared__ float wlds[8 * 1032];                  // 33 KB persistent lstm W (padded)
    __shared__ __align__(16) float smem[24576];       // 96 KB transient (h-stage / fc slabs)
    __shared__ u64 kredl[128];                        // 1 KB fc key merge

    const int blk = blockIdx.x, tid = threadIdx.x;
    const int lane = tid & 63, w = tid >> 6;
    const int u0 = blk * 2;
    unsigned* smemw = (unsigned*)smem;

    // ---- one-time: lstm W rows -> LDS (padded stride 1032) ----
    for (int i = tid; i < 8192; i += NTHR) {
        const int rowp = i >> 10, off = i & 1023;     // rowp = uu*4+q
        const int uu = rowp >> 2, q = rowp & 3;
        const int j = q * HIDDEN + u0 + uu;
        wlds[rowp * 1032 + off] = (off < 512) ? W_ih[(size_t)j * 512 + off]
                                              : W_hh[(size_t)j * 512 + off - 512];
    }

    // ---- one-time: wsplit W_fc -> Whi/Wlo (all blocks, plain stores; fenced bar 0) ----
    {
        const int nt4 = VOCAB * EMBED / 4;
        for (int i = blk * NTHR + tid; i < nt4; i += NBLK * NTHR) {
            f32x4 wv = ((const f32x4*)W_fc)[i];
            ushort_t hi[4], lo[4];
#pragma unroll
            for (int e = 0; e < 4; ++e) {
                hi[e] = f2bf(wv[e]);
                lo[e] = f2bf(wv[e] - bf2f(hi[e]));
            }
            *(uint64_t*)&Whi[i * 4] = *(const uint64_t*)hi;
            *(uint64_t*)&Wlo[i * 4] = *(const uint64_t*)lo;
        }
    }

    // ---- one-time: init (blocks 0..63): summary, h0, c0, zero out[:,0,:] ----
    if (blk < BATCH) {
        const int b = blk;
        {
            float s = 0.f;
            const float* p = enc + (size_t)b * NPIX * HIDDEN + tid;
            for (int px = 0; px < NPIX; ++px) s += p[(size_t)px * HIDDEN];
            smem[tid] = s * (1.0f / NPIX);
        }
        __syncthreads();
        {
            const int j = tid;
            const f32x4* wh = (const f32x4*)(W_init_h + (size_t)j * HIDDEN);
            const f32x4* wc = (const f32x4*)(W_init_c + (size_t)j * HIDDEN);
            float ah = 0.f, ac = 0.f;
            for (int k4 = 0; k4 < HIDDEN / 4; ++k4) {
                f32x4 s4 = *(const f32x4*)&smem[k4 * 4];
                f32x4 a = wh[k4], cc = wc[k4];
                ah += s4[0]*a[0] + s4[1]*a[1] + s4[2]*a[2] + s4[3]*a[3];
                ac += s4[0]*cc[0] + s4[1]*cc[1] + s4[2]*cc[2] + s4[3]*cc[3];
            }
            hf[b * HIDDEN + j] = __float_as_uint(ah + b_init_h[j]);   // plain (fenced bar)
            cbuf[b * HIDDEN + j] = ac + b_init_c[j];
        }
        f32x4* o4 = (f32x4*)(out + (size_t)b * MAXLEN * VOCAB);
        f32x4 z = {0.f, 0.f, 0.f, 0.f};
        for (int i = tid; i < VOCAB / 4; i += NTHR) __builtin_nontemporal_store(z, &o4[i]);
    }
    grid_barrier(barws, 0, true);

    // ======== 31 decode steps ========
    for (int t = 0; t < MAXLEN - 1; ++t) {
        const unsigned* hfin  = hf + (t & 1) * 32768;
        unsigned*       hfout = hf + ((t + 1) & 1) * 32768;

        // ---------- LSTM phase (all blocks; units u0, u0+1) ----------
        {
            const int b = tid >> 3, r = tid & 7, uu = r >> 2, q = r & 3;
            const int rowp = uu * 4 + q;
            const int j = q * HIDDEN + u0 + uu;

            int tok;
            if (t == 0) tok = captions[b * MAXLEN];
            else {
                u64 km = cld64(kslab + (size_t)(t - 1) * 1024 + b * 16);
                tok = (int)(~(unsigned)(km & 0xffffffffull));
            }

            const f32x4* x4 = (const f32x4*)(emb + (size_t)tok * EMBED);
            const f32x4* wih4 = (const f32x4*)(wlds + rowp * 1032);
            const f32x4* whh4 = wih4 + 128;

            float a = 0.f;
            for (int c = 0; c < 4; ++c) {          // 128-col h chunks, LDS rows padded to 132
                __syncthreads();
                for (int i = tid; i < 4096; i += NTHR) {
                    const int rr = i >> 6, cw = i & 63;     // cw = 2-col unit
                    u64 v = cld64((const u64*)hfin + (((size_t)rr * HIDDEN + c * 128) >> 1) + cw);
                    *(u64*)(smemw + rr * 132 + cw * 2) = v;
                }
                __syncthreads();
                const float* hs = smem + b * 132;
#pragma unroll 4
                for (int k4 = 0; k4 < 32; ++k4) {
                    const int kg = c * 32 + k4;
                    f32x4 xv = x4[kg];
                    f32x4 hv = *(const f32x4*)&hs[k4 * 4];
                    f32x4 wA = wih4[kg], vA = whh4[kg];
                    a += xv[0]*wA[0] + xv[1]*wA[1] + xv[2]*wA[2] + xv[3]*wA[3]
                       + hv[0]*vA[0] + hv[1]*vA[1] + hv[2]*vA[2] + hv[3]*vA[3];
                }
            }
            a += b_ih[j] + b_hh[j];

            const int base = (lane & ~7) + uu * 4;
            float gi  = __shfl(a, base + 0, 64);
            float gfv = __shfl(a, base + 1, 64);
            float gg  = __shfl(a, base + 2, 64);
            float go  = __shfl(a, base + 3, 64);
            float i_ = 1.f / (1.f + expf(-gi));
            float f_ = 1.f / (1.f + expf(-gfv));
            float o_ = 1.f / (1.f + expf(-go));
            float g_ = tanhf(gg);
            float cv = cbuf[b * HIDDEN + u0 + uu];
            float c2 = f_ * cv + i_ * g_;
            float h2 = o_ * tanhf(c2);
            if (q == 0) cbuf[b * HIDDEN + u0 + uu] = c2;
            float h2o = __shfl(h2, (lane & ~7) + 4, 64);   // uu=1 value
            if (r == 0) {
                ushort_t h0h = f2bf(h2),             h1h = f2bf(h2o);
                ushort_t h0l = f2bf(h2 - bf2f(h0h)), h1l = f2bf(h2o - bf2f(h1h));
                cst32(hhi32 + ((b * HIDDEN + u0) >> 1), (unsigned)h0h | ((unsigned)h1h << 16));
                cst32(hlo32 + ((b * HIDDEN + u0) >> 1), (unsigned)h0l | ((unsigned)h1l << 16));
                cst32(hfout + b * HIDDEN + u0,     __float_as_uint(h2));
                cst32(hfout + b * HIDDEN + u0 + 1, __float_as_uint(h2o));
            }
        }
        grid_barrier(barws, 1 + 2 * t, false);

        // ---------- FC phase (blocks 0..249; 2 tiles, 4-wave split-K each) ----------
        const int r16 = lane & 15, g = lane >> 4;
        const int tsel = w >> 2, ks = w & 3;
        const int tileIdx = blk * 2 + tsel;
        const int n0 = tileIdx * 64;
        if (blk < 250) {
            f32x4 acc[4][4];
#pragma unroll
            for (int i = 0; i < 4; ++i)
#pragma unroll
                for (int jj = 0; jj < 4; ++jj) acc[i][jj] = (f32x4){0.f, 0.f, 0.f, 0.f};

            const u64* hhi64 = (const u64*)hhi32;
            const u64* hlo64 = (const u64*)hlo32;
            const ushort_t* hb = Whi + (size_t)(n0 + r16) * EMBED + ks * 128 + g * 8;
            const ushort_t* lb = Wlo + (size_t)(n0 + r16) * EMBED + ks * 128 + g * 8;

#pragma unroll
            for (int kb = 0; kb < 4; ++kb) {
                const int ko = kb * 32;
                const int khere = ks * 128 + ko + g * 8;
                bf16x8 Ah[4], Al[4], Bh[4], Bl[4];
#pragma unroll
                for (int mt = 0; mt < 4; ++mt) {
                    const size_t bidx = (((size_t)(mt * 16 + r16) * 512) + khere) >> 2;
                    union { u64 d[2]; bf16x8 v; } fh, fl;
                    fh.d[0] = cld64(hhi64 + bidx); fh.d[1] = cld64(hhi64 + bidx + 1);
                    fl.d[0] = cld64(hlo64 + bidx); fl.d[1] = cld64(hlo64 + bidx + 1);
                    Ah[mt] = fh.v; Al[mt] = fl.v;
                }
#pragma unroll
                for (int nt = 0; nt < 4; ++nt) {
                    Bh[nt] = *(const bf16x8*)(hb + (size_t)nt * 16 * EMBED + ko);
                    Bl[nt] = *(const bf16x8*)(lb + (size_t)nt * 16 * EMBED + ko);
                }
#pragma unroll
                for (int mt = 0; mt < 4; ++mt)
#pragma unroll
                    for (int nt = 0; nt < 4; ++nt) {
                        acc[mt][nt] = __builtin_amdgcn_mfma_f32_16x16x32_bf16(Al[mt], Bh[nt], acc[mt][nt], 0, 0, 0);
                        acc[mt][nt] = __builtin_amdgcn_mfma_f32_16x16x32_bf16(Ah[mt], Bl[nt], acc[mt][nt], 0, 0, 0);
                        acc[mt][nt] = __builtin_amdgcn_mfma_f32_16x16x32_bf16(Ah[mt], Bh[nt], acc[mt][nt], 0, 0, 0);
                    }
            }

            // split-K reduce: waves ks=1..3 dump; wave ks=0 sums + epilogue
            if (ks != 0) {
                float* slab = smem + tsel * 12288 + (ks - 1) * 4096;
#pragma unroll
                for (int mt = 0; mt < 4; ++mt)
#pragma unroll
                    for (int nt = 0; nt < 4; ++nt)
#pragma unroll
                        for (int reg = 0; reg < 4; ++reg)
                            slab[((mt * 4 + nt) * 4 + reg) * 64 + lane] = acc[mt][nt][reg];
            }
            __syncthreads();
            if (ks == 0) {
                const float* slabs = smem + tsel * 12288;
#pragma unroll
                for (int mt = 0; mt < 4; ++mt)
#pragma unroll
                    for (int nt = 0; nt < 4; ++nt)
#pragma unroll
                        for (int reg = 0; reg < 4; ++reg) {
                            const int idx = ((mt * 4 + nt) * 4 + reg) * 64 + lane;
                            acc[mt][nt][reg] += slabs[idx] + slabs[4096 + idx] + slabs[8192 + idx];
                        }

                float bias[4];
#pragma unroll
                for (int nt = 0; nt < 4; ++nt) bias[nt] = b_fc[n0 + nt * 16 + r16];

#pragma unroll
                for (int mt = 0; mt < 4; ++mt)
#pragma unroll
                    for (int reg = 0; reg < 4; ++reg) {
                        const int row = mt * 16 + g * 4 + reg;
                        float* op = &out[(size_t)row * (MAXLEN * VOCAB) + (size_t)(t + 1) * VOCAB];
                        u64 km = 0ull;
#pragma unroll
                        for (int nt = 0; nt < 4; ++nt) {
                            const int col = n0 + nt * 16 + r16;
                            float v = acc[mt][nt][reg] + bias[nt];
                            __builtin_nontemporal_store(v, op + col);
                            u64 kk = pack_key(v, col);
                            km = kk > km ? kk : km;
                        }
#pragma unroll
                        for (int msk = 8; msk >= 1; msk >>= 1) {
                            u64 o = __shfl_xor(km, msk, 64);
                            km = km > o ? km : o;
                        }
                        if (r16 == 0) kredl[tsel * 64 + row] = km;
                    }
            }
            __syncthreads();
            if (w == 0) {   // merge 2 tiles, fire-and-forget fetch_max per padded row line
                const int row = lane;
                u64 k0 = kredl[row], k1 = kredl[64 + row];
                u64 km = k0 > k1 ? k0 : k1;
                __hip_atomic_fetch_max(kslab + (size_t)t * 1024 + row * 16, km,
                                       __ATOMIC_RELAXED, __HIP_MEMORY_SCOPE_AGENT);
            }
        }
        grid_barrier(barws, 2 + 2 * t, false);
    }
}

extern "C" void kernel_launch(void* const* d_in, const int* in_sizes, int n_in,
                              void* d_out, int out_size, void* d_ws, size_t ws_size,
                              hipStream_t stream) {
    const float* enc       = (const float*)d_in[0];
    const int*   captions  = (const int*)  d_in[1];
    const float* emb       = (const float*)d_in[2];
    const float* W_ih      = (const float*)d_in[3];
    const float* b_ih      = (const float*)d_in[4];
    const float* W_hh      = (const float*)d_in[5];
    const float* b_hh      = (const float*)d_in[6];
    const float* W_fc      = (const float*)d_in[7];
    const float* b_fc      = (const float*)d_in[8];
    const float* W_init_h  = (const float*)d_in[9];
    const float* b_init_h  = (const float*)d_in[10];
    const float* W_init_c  = (const float*)d_in[11];
    const float* b_init_c  = (const float*)d_in[12];
    float* out = (float*)d_out;

    char* wsb = (char*)d_ws;
    unsigned* hf    = (unsigned*)(wsb + 0);        // 262144B
    float*    cbuf  = (float*)(wsb + 262144);      // 131072B
    unsigned* hhi32 = (unsigned*)(wsb + 393216);   // 65536B
    unsigned* hlo32 = (unsigned*)(wsb + 458752);   // 65536B
    u64*      kslab = (u64*)(wsb + 524288);        // 253952B -> ends 778240
    unsigned* barws = (unsigned*)(wsb + 786432);   // 135168B -> ends 921600
    ushort_t* Whi   = (ushort_t*)(wsb + 1048576);  // 32768000B -> ends 33816576
    ushort_t* Wlo   = (ushort_t*)(wsb + 33816576); // 32768000B -> ends 66584576

    ws_init<<<132, 256, 0, stream>>>(barws, kslab);
    decode_all<<<NBLK, NTHR, 0, stream>>>(
        enc, captions, emb, W_ih, b_ih, W_hh, b_hh, W_fc, b_fc,
        W_init_h, b_init_h, W_init_c, b_init_c,
        out, hf, cbuf, hhi32, hlo32, kslab, Whi, Wlo, barws);
}

// Round 14
// 2185.226 us; speedup vs baseline: 1.9445x; 1.1659x over previous
//
#include <hip/hip_runtime.h>
#include <stdint.h>

#define EMBED  512
#define HIDDEN 512
#define VOCAB  32000
#define BATCH  64
#define NPIX   196
#define MAXLEN 32
#define NBLK   256
#define NTHR   512
#define NGRP   16       // 16 groups x 16 blocks (barrier tree)

typedef float f32x4 __attribute__((ext_vector_type(4)));
typedef short bf16x8 __attribute__((ext_vector_type(8)));
typedef unsigned short ushort_t;
typedef unsigned long long u64;

// ---------- helpers ----------
__device__ __forceinline__ u64 pack_key(float v, int idx) {
    unsigned u = __float_as_uint(v);
    u = (u & 0x80000000u) ? ~u : (u | 0x80000000u);   // monotone sortable map
    return ((u64)u << 32) | (unsigned)(~(unsigned)idx); // smaller idx wins ties
}
__device__ __forceinline__ ushort_t f2bf(float x) {           // round-to-nearest-even
    unsigned u = __float_as_uint(x);
    unsigned r = (u + 0x7fffu + ((u >> 16) & 1u)) >> 16;
    return (ushort_t)r;
}
__device__ __forceinline__ float bf2f(ushort_t h) {
    return __uint_as_float(((unsigned)h) << 16);
}
__device__ __forceinline__ void cst32(unsigned* p, unsigned v) {
    __hip_atomic_store(p, v, __ATOMIC_RELAXED, __HIP_MEMORY_SCOPE_AGENT);
}
__device__ __forceinline__ u64 cld64(const u64* p) {
    return __hip_atomic_load(p, __ATOMIC_RELAXED, __HIP_MEMORY_SCOPE_AGENT);
}

// ---------- tree grid barrier (R10-proven logic; slower poll backoff) ----------
__device__ __forceinline__ void grid_barrier(unsigned* barws, int k, bool fence) {
    __syncthreads();
    if (threadIdx.x == 0) {
        const int grp = blockIdx.x >> 4;
        const bool leader = (blockIdx.x & 15) == 0;
        unsigned* gc = barws + (k * NGRP + grp) * 16;
        unsigned* rc = barws + 16384 + k * 16;
        unsigned* gf = barws + 17408 + (k * NGRP + grp) * 16;
        if (fence) __threadfence();
        else asm volatile("s_waitcnt vmcnt(0)" ::: "memory");
        if (!leader) {
            __hip_atomic_fetch_add(gc, 1u, __ATOMIC_RELAXED, __HIP_MEMORY_SCOPE_AGENT);
            while (__hip_atomic_fetch_add(gf, 0u, __ATOMIC_RELAXED, __HIP_MEMORY_SCOPE_AGENT) == 0u)
                __builtin_amdgcn_s_sleep(32);
        } else {
            while (__hip_atomic_fetch_add(gc, 0u, __ATOMIC_RELAXED, __HIP_MEMORY_SCOPE_AGENT) < 15u)
                __builtin_amdgcn_s_sleep(8);
            __hip_atomic_fetch_add(rc, 1u, __ATOMIC_RELAXED, __HIP_MEMORY_SCOPE_AGENT);
            while (__hip_atomic_fetch_add(rc, 0u, __ATOMIC_RELAXED, __HIP_MEMORY_SCOPE_AGENT) < (unsigned)NGRP)
                __builtin_amdgcn_s_sleep(8);
            __hip_atomic_fetch_add(gf, 1u, __ATOMIC_RELAXED, __HIP_MEMORY_SCOPE_AGENT);
        }
        asm volatile("" ::: "memory");
    }
    __syncthreads();
}

__global__ void ws_init(unsigned* barws, u64* kslab) {
    const int i = blockIdx.x * 256 + threadIdx.x;
    if (i < 33792) barws[i] = 0u;
    if (i < 31 * 1024) kslab[i] = 0ull;      // 31 steps x 64 rows x 16-u64 stride
}

// ---------- the whole decode, one persistent kernel ----------
__global__ __launch_bounds__(512, 2) void decode_all(
    const float* __restrict__ enc,
    const int*   __restrict__ captions,
    const float* __restrict__ emb,
    const float* __restrict__ W_ih, const float* __restrict__ b_ih,
    const float* __restrict__ W_hh, const float* __restrict__ b_hh,
    const float* __restrict__ W_fc, const float* __restrict__ b_fc,
    const float* __restrict__ W_init_h, const float* __restrict__ b_init_h,
    const float* __restrict__ W_init_c, const float* __restrict__ b_init_c,
    float* __restrict__ out,
    unsigned* __restrict__ hf,      // [2][64][512] f32 bits (coherent)
    float* __restrict__ cbuf,       // block-owned units after fenced init
    unsigned* __restrict__ hhi32,   // [64][256] 2xbf16 packed (coherent)
    unsigned* __restrict__ hlo32,
    u64* __restrict__ kslab,        // [31][64][16] argmax keys (pre-zeroed)
    ushort_t* __restrict__ Whi, ushort_t* __restrict__ Wlo,
    unsigned* __restrict__ barws)
{
    __shared__ float wlds[8 * 1032];                  // 33 KB persistent lstm W (padded)
    __shared__ __align__(16) float smem[24576];       // 96 KB transient
    __shared__ u64 kredl[128];                        // 1 KB fc key merge

    const int blk = blockIdx.x, tid = threadIdx.x;
    const int lane = tid & 63, w = tid >> 6;
    const int u0 = blk * 2;

    // ---- one-time: lstm W rows -> LDS (padded stride 1032) ----
    for (int i = tid; i < 8192; i += NTHR) {
        const int rowp = i >> 10, off = i & 1023;     // rowp = uu*4+q
        const int uu = rowp >> 2, q = rowp & 3;
        const int j = q * HIDDEN + u0 + uu;
        wlds[rowp * 1032 + off] = (off < 512) ? W_ih[(size_t)j * 512 + off]
                                              : W_hh[(size_t)j * 512 + off - 512];
    }

    // ---- one-time: wsplit W_fc -> Whi/Wlo ----
    {
        const int nt4 = VOCAB * EMBED / 4;
        for (int i = blk * NTHR + tid; i < nt4; i += NBLK * NTHR) {
            f32x4 wv = ((const f32x4*)W_fc)[i];
            ushort_t hi[4], lo[4];
#pragma unroll
            for (int e = 0; e < 4; ++e) {
                hi[e] = f2bf(wv[e]);
                lo[e] = f2bf(wv[e] - bf2f(hi[e]));
            }
            *(uint64_t*)&Whi[i * 4] = *(const uint64_t*)hi;
            *(uint64_t*)&Wlo[i * 4] = *(const uint64_t*)lo;
        }
    }

    // ---- one-time: init (blocks 0..63) ----
    if (blk < BATCH) {
        const int b = blk;
        {
            float s = 0.f;
            const float* p = enc + (size_t)b * NPIX * HIDDEN + tid;
            for (int px = 0; px < NPIX; ++px) s += p[(size_t)px * HIDDEN];
            smem[tid] = s * (1.0f / NPIX);
        }
        __syncthreads();
        {
            const int j = tid;
            const f32x4* wh = (const f32x4*)(W_init_h + (size_t)j * HIDDEN);
            const f32x4* wc = (const f32x4*)(W_init_c + (size_t)j * HIDDEN);
            float ah = 0.f, ac = 0.f;
            for (int k4 = 0; k4 < HIDDEN / 4; ++k4) {
                f32x4 s4 = *(const f32x4*)&smem[k4 * 4];
                f32x4 a = wh[k4], cc = wc[k4];
                ah += s4[0]*a[0] + s4[1]*a[1] + s4[2]*a[2] + s4[3]*a[3];
                ac += s4[0]*cc[0] + s4[1]*cc[1] + s4[2]*cc[2] + s4[3]*cc[3];
            }
            hf[b * HIDDEN + j] = __float_as_uint(ah + b_init_h[j]);   // plain (fenced bar)
            cbuf[b * HIDDEN + j] = ac + b_init_c[j];
        }
        f32x4* o4 = (f32x4*)(out + (size_t)b * MAXLEN * VOCAB);
        f32x4 z = {0.f, 0.f, 0.f, 0.f};
        for (int i = tid; i < VOCAB / 4; i += NTHR) __builtin_nontemporal_store(z, &o4[i]);
    }
    grid_barrier(barws, 0, true);

    // ======== 31 decode steps ========
    for (int t = 0; t < MAXLEN - 1; ++t) {
        const unsigned* hfin  = hf + (t & 1) * 32768;
        unsigned*       hfout = hf + ((t + 1) & 1) * 32768;

        // ---------- LSTM phase (all blocks; units u0, u0+1) ----------
        {
            const int b = tid >> 3, r = tid & 7, uu = r >> 2, q = r & 3;
            const int rowp = uu * 4 + q;
            const int j = q * HIDDEN + u0 + uu;

            int tok;
            if (t == 0) tok = captions[b * MAXLEN];
            else {
                u64 km = cld64(kslab + (size_t)(t - 1) * 1024 + b * 16);
                tok = (int)(~(unsigned)(km & 0xffffffffull));
            }

            const f32x4* x4 = (const f32x4*)(emb + (size_t)tok * EMBED);
            const f32x4* wih4 = (const f32x4*)(wlds + rowp * 1032);
            const f32x4* whh4 = wih4 + 128;

            float a = 0.f;
            const int hr = tid >> 3, hc = (tid & 7) * 16;   // stage mapping
            for (int c = 0; c < 4; ++c) {          // 128-col h chunks, rows padded 132
                __syncthreads();
                {
                    const float* gp = (const float*)hfin + (size_t)hr * HIDDEN + c * 128 + hc;
                    f32x4 h0, h1, h2, h3;
                    asm volatile(
                        "global_load_dwordx4 %0, %4, off sc0 sc1\n\t"
                        "global_load_dwordx4 %1, %5, off sc0 sc1\n\t"
                        "global_load_dwordx4 %2, %6, off sc0 sc1\n\t"
                        "global_load_dwordx4 %3, %7, off sc0 sc1\n\t"
                        "s_waitcnt vmcnt(0)"
                        : "=&v"(h0), "=&v"(h1), "=&v"(h2), "=&v"(h3)
                        : "v"(gp), "v"(gp + 4), "v"(gp + 8), "v"(gp + 12)
                        : "memory");
                    float* lp = &smem[hr * 132 + hc];
                    *(f32x4*)(lp)      = h0;
                    *(f32x4*)(lp + 4)  = h1;
                    *(f32x4*)(lp + 8)  = h2;
                    *(f32x4*)(lp + 12) = h3;
                }
                __syncthreads();
                const float* hs = smem + b * 132;
#pragma unroll 4
                for (int k4 = 0; k4 < 32; ++k4) {
                    const int kg = c * 32 + k4;
                    f32x4 xv = x4[kg];
                    f32x4 hv = *(const f32x4*)&hs[k4 * 4];
                    f32x4 wA = wih4[kg], vA = whh4[kg];
                    a += xv[0]*wA[0] + xv[1]*wA[1] + xv[2]*wA[2] + xv[3]*wA[3]
                       + hv[0]*vA[0] + hv[1]*vA[1] + hv[2]*vA[2] + hv[3]*vA[3];
                }
            }
            a += b_ih[j] + b_hh[j];

            const int base = (lane & ~7) + uu * 4;
            float gi  = __shfl(a, base + 0, 64);
            float gfv = __shfl(a, base + 1, 64);
            float gg  = __shfl(a, base + 2, 64);
            float go  = __shfl(a, base + 3, 64);
            float i_ = 1.f / (1.f + expf(-gi));
            float f_ = 1.f / (1.f + expf(-gfv));
            float o_ = 1.f / (1.f + expf(-go));
            float g_ = tanhf(gg);
            float cv = cbuf[b * HIDDEN + u0 + uu];
            float c2 = f_ * cv + i_ * g_;
            float h2 = o_ * tanhf(c2);
            if (q == 0) cbuf[b * HIDDEN + u0 + uu] = c2;
            float h2o = __shfl(h2, (lane & ~7) + 4, 64);   // uu=1 value
            if (r == 0) {
                ushort_t h0h = f2bf(h2),             h1h = f2bf(h2o);
                ushort_t h0l = f2bf(h2 - bf2f(h0h)), h1l = f2bf(h2o - bf2f(h1h));
                cst32(hhi32 + ((b * HIDDEN + u0) >> 1), (unsigned)h0h | ((unsigned)h1h << 16));
                cst32(hlo32 + ((b * HIDDEN + u0) >> 1), (unsigned)h0l | ((unsigned)h1l << 16));
                cst32(hfout + b * HIDDEN + u0,     __float_as_uint(h2));
                cst32(hfout + b * HIDDEN + u0 + 1, __float_as_uint(h2o));
            }
        }
        grid_barrier(barws, 1 + 2 * t, false);

        // ---------- FC phase (blocks 0..249; 2 tiles, 4-wave split-K each) ----------
        const int r16 = lane & 15, g = lane >> 4;
        const int tsel = w >> 2, ks = w & 3;
        const int tileIdx = blk * 2 + tsel;
        const int n0 = tileIdx * 64;
        if (blk < 250) {
            f32x4 acc[4][4];
#pragma unroll
            for (int i = 0; i < 4; ++i)
#pragma unroll
                for (int jj = 0; jj < 4; ++jj) acc[i][jj] = (f32x4){0.f, 0.f, 0.f, 0.f};

            const ushort_t* hb = Whi + (size_t)(n0 + r16) * EMBED + ks * 128 + g * 8;
            const ushort_t* lb = Wlo + (size_t)(n0 + r16) * EMBED + ks * 128 + g * 8;

#pragma unroll
            for (int kb = 0; kb < 4; ++kb) {
                const int ko = kb * 32;
                const int w32 = ks * 64 + kb * 16 + g * 4;   // u32 index of A-frag
                bf16x8 Ah[4], Al[4], Bh[4], Bl[4];
                {
                    const unsigned* h0 = hhi32 + (size_t)(r16)      * 256 + w32;
                    const unsigned* h1 = hhi32 + (size_t)(16 + r16) * 256 + w32;
                    const unsigned* h2 = hhi32 + (size_t)(32 + r16) * 256 + w32;
                    const unsigned* h3 = hhi32 + (size_t)(48 + r16) * 256 + w32;
                    const unsigned* l0 = hlo32 + (size_t)(r16)      * 256 + w32;
                    const unsigned* l1 = hlo32 + (size_t)(16 + r16) * 256 + w32;
                    const unsigned* l2 = hlo32 + (size_t)(32 + r16) * 256 + w32;
                    const unsigned* l3 = hlo32 + (size_t)(48 + r16) * 256 + w32;
                    asm volatile(
                        "global_load_dwordx4 %0, %8,  off sc0 sc1\n\t"
                        "global_load_dwordx4 %1, %9,  off sc0 sc1\n\t"
                        "global_load_dwordx4 %2, %10, off sc0 sc1\n\t"
                        "global_load_dwordx4 %3, %11, off sc0 sc1\n\t"
                        "global_load_dwordx4 %4, %12, off sc0 sc1\n\t"
                        "global_load_dwordx4 %5, %13, off sc0 sc1\n\t"
                        "global_load_dwordx4 %6, %14, off sc0 sc1\n\t"
                        "global_load_dwordx4 %7, %15, off sc0 sc1\n\t"
                        "s_waitcnt vmcnt(0)"
                        : "=&v"(Ah[0]), "=&v"(Ah[1]), "=&v"(Ah[2]), "=&v"(Ah[3]),
                          "=&v"(Al[0]), "=&v"(Al[1]), "=&v"(Al[2]), "=&v"(Al[3])
                        : "v"(h0), "v"(h1), "v"(h2), "v"(h3),
                          "v"(l0), "v"(l1), "v"(l2), "v"(l3)
                        : "memory");
                }
#pragma unroll
                for (int nt = 0; nt < 4; ++nt) {
                    Bh[nt] = *(const bf16x8*)(hb + (size_t)nt * 16 * EMBED + ko);
                    Bl[nt] = *(const bf16x8*)(lb + (size_t)nt * 16 * EMBED + ko);
                }
#pragma unroll
                for (int mt = 0; mt < 4; ++mt)
#pragma unroll
                    for (int nt = 0; nt < 4; ++nt) {
                        acc[mt][nt] = __builtin_amdgcn_mfma_f32_16x16x32_bf16(Al[mt], Bh[nt], acc[mt][nt], 0, 0, 0);
                        acc[mt][nt] = __builtin_amdgcn_mfma_f32_16x16x32_bf16(Ah[mt], Bl[nt], acc[mt][nt], 0, 0, 0);
                        acc[mt][nt] = __builtin_amdgcn_mfma_f32_16x16x32_bf16(Ah[mt], Bh[nt], acc[mt][nt], 0, 0, 0);
                    }
            }

            // split-K reduce: waves ks=1..3 dump; wave ks=0 sums + epilogue
            if (ks != 0) {
                float* slab = smem + tsel * 12288 + (ks - 1) * 4096;
#pragma unroll
                for (int mt = 0; mt < 4; ++mt)
#pragma unroll
                    for (int nt = 0; nt < 4; ++nt)
#pragma unroll
                        for (int reg = 0; reg < 4; ++reg)
                            slab[((mt * 4 + nt) * 4 + reg) * 64 + lane] = acc[mt][nt][reg];
            }
            __syncthreads();
            if (ks == 0) {
                const float* slabs = smem + tsel * 12288;
#pragma unroll
                for (int mt = 0; mt < 4; ++mt)
#pragma unroll
                    for (int nt = 0; nt < 4; ++nt)
#pragma unroll
                        for (int reg = 0; reg < 4; ++reg) {
                            const int idx = ((mt * 4 + nt) * 4 + reg) * 64 + lane;
                            acc[mt][nt][reg] += slabs[idx] + slabs[4096 + idx] + slabs[8192 + idx];
                        }

                float bias[4];
#pragma unroll
                for (int nt = 0; nt < 4; ++nt) bias[nt] = b_fc[n0 + nt * 16 + r16];

#pragma unroll
                for (int mt = 0; mt < 4; ++mt)
#pragma unroll
                    for (int reg = 0; reg < 4; ++reg) {
                        const int row = mt * 16 + g * 4 + reg;
                        float* op = &out[(size_t)row * (MAXLEN * VOCAB) + (size_t)(t + 1) * VOCAB];
                        u64 km = 0ull;
#pragma unroll
                        for (int nt = 0; nt < 4; ++nt) {
                            const int col = n0 + nt * 16 + r16;
                            float v = acc[mt][nt][reg] + bias[nt];
                            __builtin_nontemporal_store(v, op + col);
                            u64 kk = pack_key(v, col);
                            km = kk > km ? kk : km;
                        }
#pragma unroll
                        for (int msk = 8; msk >= 1; msk >>= 1) {
                            u64 o = __shfl_xor(km, msk, 64);
                            km = km > o ? km : o;
                        }
                        if (r16 == 0) kredl[tsel * 64 + row] = km;
                    }
            }
            __syncthreads();
            if (w == 0) {   // merge 2 tiles, fire-and-forget fetch_max per padded row line
                const int row = lane;
                u64 k0 = kredl[row], k1 = kredl[64 + row];
                u64 km = k0 > k1 ? k0 : k1;
                __hip_atomic_fetch_max(kslab + (size_t)t * 1024 + row * 16, km,
                                       __ATOMIC_RELAXED, __HIP_MEMORY_SCOPE_AGENT);
            }
        }
        grid_barrier(barws, 2 + 2 * t, false);
    }
}

extern "C" void kernel_launch(void* const* d_in, const int* in_sizes, int n_in,
                              void* d_out, int out_size, void* d_ws, size_t ws_size,
                              hipStream_t stream) {
    const float* enc       = (const float*)d_in[0];
    const int*   captions  = (const int*)  d_in[1];
    const float* emb       = (const float*)d_in[2];
    const float* W_ih      = (const float*)d_in[3];
    const float* b_ih      = (const float*)d_in[4];
    const float* W_hh      = (const float*)d_in[5];
    const float* b_hh      = (const float*)d_in[6];
    const float* W_fc      = (const float*)d_in[7];
    const float* b_fc      = (const float*)d_in[8];
    const float* W_init_h  = (const float*)d_in[9];
    const float* b_init_h  = (const float*)d_in[10];
    const float* W_init_c  = (const float*)d_in[11];
    const float* b_init_c  = (const float*)d_in[12];
    float* out = (float*)d_out;

    char* wsb = (char*)d_ws;
    unsigned* hf    = (unsigned*)(wsb + 0);        // 262144B
    float*    cbuf  = (float*)(wsb + 262144);      // 131072B
    unsigned* hhi32 = (unsigned*)(wsb + 393216);   // 65536B
    unsigned* hlo32 = (unsigned*)(wsb + 458752);   // 65536B
    u64*      kslab = (u64*)(wsb + 524288);        // 253952B -> ends 778240
    unsigned* barws = (unsigned*)(wsb + 786432);   // 135168B -> ends 921600
    ushort_t* Whi   = (ushort_t*)(wsb + 1048576);  // 32768000B -> ends 33816576
    ushort_t* Wlo   = (ushort_t*)(wsb + 33816576); // 32768000B -> ends 66584576

    ws_init<<<132, 256, 0, stream>>>(barws, kslab);
    decode_all<<<NBLK, NTHR, 0, stream>>>(
        enc, captions, emb, W_ih, b_ih, W_hh, b_hh, W_fc, b_fc,
        W_init_h, b_init_h, W_init_c, b_init_c,
        out, hf, cbuf, hhi32, hlo32, kslab, Whi, Wlo, barws);
}

// Round 15
// 1880.339 us; speedup vs baseline: 2.2598x; 1.1621x over previous
//
#include <hip/hip_runtime.h>
#include <stdint.h>

#define EMBED  512
#define HIDDEN 512
#define VOCAB  32000
#define BATCH  64
#define NPIX   196
#define MAXLEN 32
#define NBLK   256
#define NTHR   512
#define NGRP   16       // 16 groups x 16 blocks (barrier tree)

typedef float f32x4 __attribute__((ext_vector_type(4)));
typedef short bf16x8 __attribute__((ext_vector_type(8)));
typedef unsigned short ushort_t;
typedef unsigned long long u64;

// ---------- helpers ----------
__device__ __forceinline__ u64 pack_key(float v, int idx) {
    unsigned u = __float_as_uint(v);
    u = (u & 0x80000000u) ? ~u : (u | 0x80000000u);   // monotone sortable map
    return ((u64)u << 32) | (unsigned)(~(unsigned)idx); // smaller idx wins ties
}
__device__ __forceinline__ ushort_t f2bf(float x) {           // round-to-nearest-even
    unsigned u = __float_as_uint(x);
    unsigned r = (u + 0x7fffu + ((u >> 16) & 1u)) >> 16;
    return (ushort_t)r;
}
__device__ __forceinline__ float bf2f(ushort_t h) {
    return __uint_as_float(((unsigned)h) << 16);
}
__device__ __forceinline__ void cst32(unsigned* p, unsigned v) {
    __hip_atomic_store(p, v, __ATOMIC_RELAXED, __HIP_MEMORY_SCOPE_AGENT);
}
__device__ __forceinline__ u64 cld64(const u64* p) {
    return __hip_atomic_load(p, __ATOMIC_RELAXED, __HIP_MEMORY_SCOPE_AGENT);
}

// ---------- tree grid barrier (R10-proven; R14 backoff) ----------
__device__ __forceinline__ void grid_barrier(unsigned* barws, int k, bool fence) {
    __syncthreads();
    if (threadIdx.x == 0) {
        const int grp = blockIdx.x >> 4;
        const bool leader = (blockIdx.x & 15) == 0;
        unsigned* gc = barws + (k * NGRP + grp) * 16;
        unsigned* rc = barws + 16384 + k * 16;
        unsigned* gf = barws + 17408 + (k * NGRP + grp) * 16;
        if (fence) __threadfence();
        else asm volatile("s_waitcnt vmcnt(0)" ::: "memory");
        if (!leader) {
            __hip_atomic_fetch_add(gc, 1u, __ATOMIC_RELAXED, __HIP_MEMORY_SCOPE_AGENT);
            while (__hip_atomic_fetch_add(gf, 0u, __ATOMIC_RELAXED, __HIP_MEMORY_SCOPE_AGENT) == 0u)
                __builtin_amdgcn_s_sleep(32);
        } else {
            while (__hip_atomic_fetch_add(gc, 0u, __ATOMIC_RELAXED, __HIP_MEMORY_SCOPE_AGENT) < 15u)
                __builtin_amdgcn_s_sleep(8);
            __hip_atomic_fetch_add(rc, 1u, __ATOMIC_RELAXED, __HIP_MEMORY_SCOPE_AGENT);
            while (__hip_atomic_fetch_add(rc, 0u, __ATOMIC_RELAXED, __HIP_MEMORY_SCOPE_AGENT) < (unsigned)NGRP)
                __builtin_amdgcn_s_sleep(8);
            __hip_atomic_fetch_add(gf, 1u, __ATOMIC_RELAXED, __HIP_MEMORY_SCOPE_AGENT);
        }
        asm volatile("" ::: "memory");
    }
    __syncthreads();
}

__global__ void ws_init(unsigned* barws, u64* kslab) {
    const int i = blockIdx.x * 256 + threadIdx.x;
    if (i < 33792) barws[i] = 0u;
    if (i < 31 * 1024) kslab[i] = 0ull;      // 31 steps x 64 rows x 16-u64 stride
}

// ---------- the whole decode, one persistent kernel ----------
// Fresh-slab-per-step h buffers: writes are agent atomic stores (write-through),
// reads are PLAIN cached loads — address never previously touched by the reader
// CU, so L2 miss -> coherence point -> fresh data, then cached.
__global__ __launch_bounds__(512, 2) void decode_all(
    const float* __restrict__ enc,
    const int*   __restrict__ captions,
    const float* __restrict__ emb,
    const float* __restrict__ W_ih, const float* __restrict__ b_ih,
    const float* __restrict__ W_hh, const float* __restrict__ b_hh,
    const float* __restrict__ W_fc, const float* __restrict__ b_fc,
    const float* __restrict__ W_init_h, const float* __restrict__ b_init_h,
    const float* __restrict__ W_init_c, const float* __restrict__ b_init_c,
    float* __restrict__ out,
    float* __restrict__ cbuf,       // block-owned units after fenced init
    float* __restrict__ hfs,        // [32][64][512] f32 h slabs (slab t = input to step t)
    unsigned* __restrict__ hhis,    // [31][64][256] packed 2xbf16 hi slabs
    unsigned* __restrict__ hlos,    // [31][64][256] packed 2xbf16 lo slabs
    u64* __restrict__ kslab,        // [31][64][16] argmax keys (pre-zeroed)
    ushort_t* __restrict__ Whi, ushort_t* __restrict__ Wlo,
    unsigned* __restrict__ barws)
{
    __shared__ float wlds[8 * 1032];                  // 33 KB persistent lstm W (padded)
    __shared__ __align__(16) float smem[24576];       // 96 KB transient
    __shared__ u64 kredl[128];                        // 1 KB fc key merge

    const int blk = blockIdx.x, tid = threadIdx.x;
    const int lane = tid & 63, w = tid >> 6;
    const int u0 = blk * 2;

    // ---- one-time: lstm W rows -> LDS (padded stride 1032) ----
    for (int i = tid; i < 8192; i += NTHR) {
        const int rowp = i >> 10, off = i & 1023;     // rowp = uu*4+q
        const int uu = rowp >> 2, q = rowp & 3;
        const int j = q * HIDDEN + u0 + uu;
        wlds[rowp * 1032 + off] = (off < 512) ? W_ih[(size_t)j * 512 + off]
                                              : W_hh[(size_t)j * 512 + off - 512];
    }

    // ---- one-time: wsplit W_fc -> Whi/Wlo ----
    {
        const int nt4 = VOCAB * EMBED / 4;
        for (int i = blk * NTHR + tid; i < nt4; i += NBLK * NTHR) {
            f32x4 wv = ((const f32x4*)W_fc)[i];
            ushort_t hi[4], lo[4];
#pragma unroll
            for (int e = 0; e < 4; ++e) {
                hi[e] = f2bf(wv[e]);
                lo[e] = f2bf(wv[e] - bf2f(hi[e]));
            }
            *(uint64_t*)&Whi[i * 4] = *(const uint64_t*)hi;
            *(uint64_t*)&Wlo[i * 4] = *(const uint64_t*)lo;
        }
    }

    // ---- one-time: init (blocks 0..63) ----
    if (blk < BATCH) {
        const int b = blk;
        {
            float s = 0.f;
            const float* p = enc + (size_t)b * NPIX * HIDDEN + tid;
            for (int px = 0; px < NPIX; ++px) s += p[(size_t)px * HIDDEN];
            smem[tid] = s * (1.0f / NPIX);
        }
        __syncthreads();
        {
            const int j = tid;
            const f32x4* wh = (const f32x4*)(W_init_h + (size_t)j * HIDDEN);
            const f32x4* wc = (const f32x4*)(W_init_c + (size_t)j * HIDDEN);
            float ah = 0.f, ac = 0.f;
            for (int k4 = 0; k4 < HIDDEN / 4; ++k4) {
                f32x4 s4 = *(const f32x4*)&smem[k4 * 4];
                f32x4 a = wh[k4], cc = wc[k4];
                ah += s4[0]*a[0] + s4[1]*a[1] + s4[2]*a[2] + s4[3]*a[3];
                ac += s4[0]*cc[0] + s4[1]*cc[1] + s4[2]*cc[2] + s4[3]*cc[3];
            }
            hfs[b * HIDDEN + j] = ah + b_init_h[j];          // slab 0, plain (fenced bar)
            cbuf[b * HIDDEN + j] = ac + b_init_c[j];
        }
        f32x4* o4 = (f32x4*)(out + (size_t)b * MAXLEN * VOCAB);
        f32x4 z = {0.f, 0.f, 0.f, 0.f};
        for (int i = tid; i < VOCAB / 4; i += NTHR) __builtin_nontemporal_store(z, &o4[i]);
    }
    grid_barrier(barws, 0, true);

    // ======== 31 decode steps ========
    for (int t = 0; t < MAXLEN - 1; ++t) {
        const float* hfin  = hfs + (size_t)t * 32768;        // slab t (read-only now)
        unsigned*    hfout = (unsigned*)(hfs + (size_t)(t + 1) * 32768);
        const unsigned* hhi_t = hhis + (size_t)t * 16384;
        const unsigned* hlo_t = hlos + (size_t)t * 16384;

        // ---------- LSTM phase (all blocks; units u0, u0+1) ----------
        {
            const int b = tid >> 3, r = tid & 7, uu = r >> 2, q = r & 3;
            const int rowp = uu * 4 + q;
            const int j = q * HIDDEN + u0 + uu;

            int tok;
            if (t == 0) tok = captions[b * MAXLEN];
            else {
                u64 km = cld64(kslab + (size_t)(t - 1) * 1024 + b * 16);
                tok = (int)(~(unsigned)(km & 0xffffffffull));
            }

            const f32x4* x4 = (const f32x4*)(emb + (size_t)tok * EMBED);
            const f32x4* wih4 = (const f32x4*)(wlds + rowp * 1032);
            const f32x4* whh4 = wih4 + 128;

            float a = 0.f;
            const int hr = tid >> 3, hc = (tid & 7) * 16;   // stage mapping
            for (int c = 0; c < 4; ++c) {          // 128-col h chunks, rows padded 132
                __syncthreads();
                {
                    const f32x4* gp = (const f32x4*)(hfin + (size_t)hr * HIDDEN + c * 128 + hc);
                    f32x4 h0 = gp[0], h1 = gp[1], h2 = gp[2], h3 = gp[3];
                    float* lp = &smem[hr * 132 + hc];
                    *(f32x4*)(lp)      = h0;
                    *(f32x4*)(lp + 4)  = h1;
                    *(f32x4*)(lp + 8)  = h2;
                    *(f32x4*)(lp + 12) = h3;
                }
                __syncthreads();
                const float* hs = smem + b * 132;
#pragma unroll 4
                for (int k4 = 0; k4 < 32; ++k4) {
                    const int kg = c * 32 + k4;
                    f32x4 xv = x4[kg];
                    f32x4 hv = *(const f32x4*)&hs[k4 * 4];
                    f32x4 wA = wih4[kg], vA = whh4[kg];
                    a += xv[0]*wA[0] + xv[1]*wA[1] + xv[2]*wA[2] + xv[3]*wA[3]
                       + hv[0]*vA[0] + hv[1]*vA[1] + hv[2]*vA[2] + hv[3]*vA[3];
                }
            }
            a += b_ih[j] + b_hh[j];

            const int base = (lane & ~7) + uu * 4;
            float gi  = __shfl(a, base + 0, 64);
            float gfv = __shfl(a, base + 1, 64);
            float gg  = __shfl(a, base + 2, 64);
            float go  = __shfl(a, base + 3, 64);
            float i_ = 1.f / (1.f + expf(-gi));
            float f_ = 1.f / (1.f + expf(-gfv));
            float o_ = 1.f / (1.f + expf(-go));
            float g_ = tanhf(gg);
            float cv = cbuf[b * HIDDEN + u0 + uu];
            float c2 = f_ * cv + i_ * g_;
            float h2 = o_ * tanhf(c2);
            if (q == 0) cbuf[b * HIDDEN + u0 + uu] = c2;
            float h2o = __shfl(h2, (lane & ~7) + 4, 64);   // uu=1 value
            if (r == 0) {
                ushort_t h0h = f2bf(h2),             h1h = f2bf(h2o);
                ushort_t h0l = f2bf(h2 - bf2f(h0h)), h1l = f2bf(h2o - bf2f(h1h));
                cst32((unsigned*)hhis + (size_t)t * 16384 + ((b * HIDDEN + u0) >> 1),
                      (unsigned)h0h | ((unsigned)h1h << 16));
                cst32((unsigned*)hlos + (size_t)t * 16384 + ((b * HIDDEN + u0) >> 1),
                      (unsigned)h0l | ((unsigned)h1l << 16));
                cst32(hfout + b * HIDDEN + u0,     __float_as_uint(h2));
                cst32(hfout + b * HIDDEN + u0 + 1, __float_as_uint(h2o));
            }
        }
        grid_barrier(barws, 1 + 2 * t, false);

        // ---------- FC phase (blocks 0..249; 2 tiles, 4-wave split-K each) ----------
        const int r16 = lane & 15, g = lane >> 4;
        const int tsel = w >> 2, ks = w & 3;
        const int tileIdx = blk * 2 + tsel;
        const int n0 = tileIdx * 64;
        if (blk < 250) {
            f32x4 acc[4][4];
#pragma unroll
            for (int i = 0; i < 4; ++i)
#pragma unroll
                for (int jj = 0; jj < 4; ++jj) acc[i][jj] = (f32x4){0.f, 0.f, 0.f, 0.f};

            const ushort_t* hb = Whi + (size_t)(n0 + r16) * EMBED + ks * 128 + g * 8;
            const ushort_t* lb = Wlo + (size_t)(n0 + r16) * EMBED + ks * 128 + g * 8;

#pragma unroll
            for (int kb = 0; kb < 4; ++kb) {
                const int ko = kb * 32;
                const int w32 = ks * 64 + kb * 16 + g * 4;   // u32 index of A-frag
                bf16x8 Ah[4], Al[4], Bh[4], Bl[4];
#pragma unroll
                for (int mt = 0; mt < 4; ++mt) {
                    Ah[mt] = *(const bf16x8*)(hhi_t + (size_t)(mt * 16 + r16) * 256 + w32);
                    Al[mt] = *(const bf16x8*)(hlo_t + (size_t)(mt * 16 + r16) * 256 + w32);
                }
#pragma unroll
                for (int nt = 0; nt < 4; ++nt) {
                    Bh[nt] = *(const bf16x8*)(hb + (size_t)nt * 16 * EMBED + ko);
                    Bl[nt] = *(const bf16x8*)(lb + (size_t)nt * 16 * EMBED + ko);
                }
#pragma unroll
                for (int mt = 0; mt < 4; ++mt)
#pragma unroll
                    for (int nt = 0; nt < 4; ++nt) {
                        acc[mt][nt] = __builtin_amdgcn_mfma_f32_16x16x32_bf16(Al[mt], Bh[nt], acc[mt][nt], 0, 0, 0);
                        acc[mt][nt] = __builtin_amdgcn_mfma_f32_16x16x32_bf16(Ah[mt], Bl[nt], acc[mt][nt], 0, 0, 0);
                        acc[mt][nt] = __builtin_amdgcn_mfma_f32_16x16x32_bf16(Ah[mt], Bh[nt], acc[mt][nt], 0, 0, 0);
                    }
            }

            // split-K reduce: waves ks=1..3 dump; wave ks=0 sums + epilogue
            if (ks != 0) {
                float* slab = smem + tsel * 12288 + (ks - 1) * 4096;
#pragma unroll
                for (int mt = 0; mt < 4; ++mt)
#pragma unroll
                    for (int nt = 0; nt < 4; ++nt)
#pragma unroll
                        for (int reg = 0; reg < 4; ++reg)
                            slab[((mt * 4 + nt) * 4 + reg) * 64 + lane] = acc[mt][nt][reg];
            }
            __syncthreads();
            if (ks == 0) {
                const float* slabs = smem + tsel * 12288;
#pragma unroll
                for (int mt = 0; mt < 4; ++mt)
#pragma unroll
                    for (int nt = 0; nt < 4; ++nt)
#pragma unroll
                        for (int reg = 0; reg < 4; ++reg) {
                            const int idx = ((mt * 4 + nt) * 4 + reg) * 64 + lane;
                            acc[mt][nt][reg] += slabs[idx] + slabs[4096 + idx] + slabs[8192 + idx];
                        }

                float bias[4];
#pragma unroll
                for (int nt = 0; nt < 4; ++nt) bias[nt] = b_fc[n0 + nt * 16 + r16];

#pragma unroll
                for (int mt = 0; mt < 4; ++mt)
#pragma unroll
                    for (int reg = 0; reg < 4; ++reg) {
                        const int row = mt * 16 + g * 4 + reg;
                        float* op = &out[(size_t)row * (MAXLEN * VOCAB) + (size_t)(t + 1) * VOCAB];
                        u64 km = 0ull;
#pragma unroll
                        for (int nt = 0; nt < 4; ++nt) {
                            const int col = n0 + nt * 16 + r16;
                            float v = acc[mt][nt][reg] + bias[nt];
                            __builtin_nontemporal_store(v, op + col);
                            u64 kk = pack_key(v, col);
                            km = kk > km ? kk : km;
                        }
#pragma unroll
                        for (int msk = 8; msk >= 1; msk >>= 1) {
                            u64 o = __shfl_xor(km, msk, 64);
                            km = km > o ? km : o;
                        }
                        if (r16 == 0) kredl[tsel * 64 + row] = km;
                    }
            }
            __syncthreads();
            if (w == 0) {   // merge 2 tiles, fire-and-forget fetch_max per padded row line
                const int row = lane;
                u64 k0 = kredl[row], k1 = kredl[64 + row];
                u64 km = k0 > k1 ? k0 : k1;
                __hip_atomic_fetch_max(kslab + (size_t)t * 1024 + row * 16, km,
                                       __ATOMIC_RELAXED, __HIP_MEMORY_SCOPE_AGENT);
            }
        }
        grid_barrier(barws, 2 + 2 * t, false);
    }
}

extern "C" void kernel_launch(void* const* d_in, const int* in_sizes, int n_in,
                              void* d_out, int out_size, void* d_ws, size_t ws_size,
                              hipStream_t stream) {
    const float* enc       = (const float*)d_in[0];
    const int*   captions  = (const int*)  d_in[1];
    const float* emb       = (const float*)d_in[2];
    const float* W_ih      = (const float*)d_in[3];
    const float* b_ih      = (const float*)d_in[4];
    const float* W_hh      = (const float*)d_in[5];
    const float* b_hh      = (const float*)d_in[6];
    const float* W_fc      = (const float*)d_in[7];
    const float* b_fc      = (const float*)d_in[8];
    const float* W_init_h  = (const float*)d_in[9];
    const float* b_init_h  = (const float*)d_in[10];
    const float* W_init_c  = (const float*)d_in[11];
    const float* b_init_c  = (const float*)d_in[12];
    float* out = (float*)d_out;

    char* wsb = (char*)d_ws;
    float*    cbuf  = (float*)(wsb + 0);           // 131072B
    u64*      kslab = (u64*)(wsb + 131072);        // 253952B -> ends 385024
    unsigned* barws = (unsigned*)(wsb + 393216);   // 135168B -> ends 528384
    float*    hfs   = (float*)(wsb + 1048576);     // 32 x 131072B -> ends 5242880
    unsigned* hhis  = (unsigned*)(wsb + 5242880);  // 31 x 65536B -> ends 7274496
    unsigned* hlos  = (unsigned*)(wsb + 7274496);  // 31 x 65536B -> ends 9306112
    ushort_t* Whi   = (ushort_t*)(wsb + 9437184);  // 32768000B -> ends 42205184
    ushort_t* Wlo   = (ushort_t*)(wsb + 42205184); // 32768000B -> ends 74973184

    ws_init<<<132, 256, 0, stream>>>(barws, kslab);
    decode_all<<<NBLK, NTHR, 0, stream>>>(
        enc, captions, emb, W_ih, b_ih, W_hh, b_hh, W_fc, b_fc,
        W_init_h, b_init_h, W_init_c, b_init_c,
        out, cbuf, hfs, hhis, hlos, kslab, Whi, Wlo, barws);
}